// Round 1
// baseline (2941.509 us; speedup 1.0000x reference)
//
#include <hip/hip_runtime.h>
#include <hip/hip_bf16.h>
#include <cstdint>
#include <cstddef>

typedef __bf16 bf16_t;
typedef __bf16 bf16x8 __attribute__((ext_vector_type(8)));
typedef __bf16 bf16x4 __attribute__((ext_vector_type(4)));
typedef float  f32x4  __attribute__((ext_vector_type(4)));

#define B_  32
#define T_  128
#define H_  512
#define V_  32000
#define G4_ 2048   // 4*H

// ---------------- prep kernels ----------------

__global__ void convert_f32_bf16(const float* __restrict__ src, bf16_t* __restrict__ dst, int n4) {
  int i = blockIdx.x * blockDim.x + threadIdx.x;
  int stride = gridDim.x * blockDim.x;
  for (; i < n4; i += stride) {
    float4 v = ((const float4*)src)[i];
    bf16x4 o = { (bf16_t)v.x, (bf16_t)v.y, (bf16_t)v.z, (bf16_t)v.w };
    ((bf16x4*)dst)[i] = o;
  }
}

// One block per (b,t) row: tok = t==0 ? START_IDX(1) : target[b,t-1]; Xemb[row] = bf16(E[tok])
__global__ void gather_embed(const float* __restrict__ E, const int* __restrict__ target,
                             bf16_t* __restrict__ Xemb) {
  int n = blockIdx.x;               // 0..4095, row = b*T + t
  int b = n >> 7, t = n & 127;
  int tok = (t == 0) ? 1 : target[b * T_ + t - 1];
  const float4* src = (const float4*)(E + (size_t)tok * H_);
  bf16x4* dst = (bf16x4*)(Xemb + (size_t)n * H_);
  int k = threadIdx.x;              // 128 threads * 4 floats = 512
  float4 v = src[k];
  bf16x4 o = { (bf16_t)v.x, (bf16_t)v.y, (bf16_t)v.z, (bf16_t)v.w };
  dst[k] = o;
}

// h0 = c0 = encoder_output_state; bsum = b_ih + b_hh
__global__ void init_state(const float* __restrict__ enc, const float* __restrict__ b_ih,
                           const float* __restrict__ b_hh, float* __restrict__ h0,
                           float* __restrict__ c0, float* __restrict__ bsum) {
  int i = blockIdx.x * blockDim.x + threadIdx.x;  // 64*256 = 16384 = 32*512
  h0[i] = enc[i];
  c0[i] = enc[i];
  if (i < G4_) bsum[i] = b_ih[i] + b_hh[i];
}

// ---------------- bf16 MFMA GEMM: C[M,N] = A[M,512] * B[N,512]^T + bias[N] ----------------
// m97 structure: 128x128 tile, BK=64, 256 threads (4 waves, 2x2 of 64x64),
// global_load_lds width-16 staging, mfma_f32_16x16x32_bf16.
// Requires M%128==0, N%128==0, K==512.
__global__ __launch_bounds__(256)
void gemm_bt(const bf16_t* __restrict__ A, const bf16_t* __restrict__ Bm,
             const float* __restrict__ bias, float* __restrict__ C, int N) {
  __shared__ bf16_t As[128 * 64];
  __shared__ bf16_t Bs[128 * 64];
  const int tid  = threadIdx.x;
  const int tn   = blockIdx.x;      // N / 128
  const int tm   = blockIdx.y;      // M / 128
  const int lane = tid & 63, wid = tid >> 6;
  const int wm = (wid >> 1) * 64, wn = (wid & 1) * 64;
  const size_t K = 512;

  f32x4 acc[4][4] = {};

  for (int k0 = 0; k0 < 512; k0 += 64) {
    // stage A-tile and B-tile: 16KB each, 4 rounds of 256 lanes x 16B
    #pragma unroll
    for (int r = 0; r < 4; ++r) {
      int c   = r * 256 + tid;      // chunk index 0..1023
      int row = c >> 3, kc = c & 7; // row 0..127, 16B-chunk 0..7 within 64-k slice
      const bf16_t* ga = A  + ((size_t)(tm * 128 + row)) * K + (size_t)k0 + kc * 8;
      const bf16_t* gb = Bm + ((size_t)(tn * 128 + row)) * K + (size_t)k0 + kc * 8;
      __builtin_amdgcn_global_load_lds((__attribute__((address_space(1))) void*)ga,
                                       (__attribute__((address_space(3))) void*)(As + c * 8),
                                       16, 0, 0);
      __builtin_amdgcn_global_load_lds((__attribute__((address_space(1))) void*)gb,
                                       (__attribute__((address_space(3))) void*)(Bs + c * 8),
                                       16, 0, 0);
    }
    __syncthreads();

    #pragma unroll
    for (int k32 = 0; k32 < 64; k32 += 32) {
      bf16x8 af[4], bfr[4];
      const int kk = k32 + (lane >> 4) * 8;
      #pragma unroll
      for (int i = 0; i < 4; ++i) {
        int ra = wm + i * 16 + (lane & 15);
        af[i]  = *(const bf16x8*)(As + ra * 64 + kk);
        int rb = wn + i * 16 + (lane & 15);
        bfr[i] = *(const bf16x8*)(Bs + rb * 64 + kk);
      }
      #pragma unroll
      for (int i = 0; i < 4; ++i)
        #pragma unroll
        for (int j = 0; j < 4; ++j)
          acc[i][j] = __builtin_amdgcn_mfma_f32_16x16x32_bf16(af[i], bfr[j], acc[i][j], 0, 0, 0);
    }
    __syncthreads();
  }

  // epilogue: C/D layout col = lane&15 (n), row = (lane>>4)*4 + reg (m)  [m89-verified]
  const int m0 = tm * 128 + wm + (lane >> 4) * 4;
  const int n0 = tn * 128 + wn + (lane & 15);
  #pragma unroll
  for (int i = 0; i < 4; ++i) {
    #pragma unroll
    for (int j = 0; j < 4; ++j) {
      int nn = n0 + j * 16;
      float bv = bias ? bias[nn] : 0.f;
      #pragma unroll
      for (int r = 0; r < 4; ++r) {
        int mm = m0 + i * 16 + r;
        C[(size_t)mm * N + nn] = acc[i][j][r] + bv;
      }
    }
  }
}

// ---------------- LSTM recurrence step (f32, one kernel per t) ----------------
// grid 256 blocks: block = (b4 in 0..7 [4 batch rows], mc in 0..31 [16 m-values -> 64 gate rows])
// thread tid: jl = tid&63 -> gate = jl>>4, ml = jl&15 ; bl = tid>>6 (4 b's)
__global__ __launch_bounds__(256)
void lstm_step(int t, const float* __restrict__ Xg, const float* __restrict__ Whh,
               const float* __restrict__ hin, float* __restrict__ hout,
               float* __restrict__ cbuf, bf16_t* __restrict__ Hall) {
  __shared__ float hsh[4 * 512];    // 4 batch rows of h
  __shared__ float gsh[4 * 64];     // [bl][gate*16+ml] gate pre-activations
  const int blk = blockIdx.x;
  const int b4 = blk >> 5;          // 0..7
  const int mc = blk & 31;          // 0..31
  const int tid = threadIdx.x;

  { // stage 4 rows of h_prev into LDS (256 threads x 8 floats)
    int i = tid * 8;
    const float4* src = (const float4*)(hin + (size_t)b4 * 4 * H_ + i);
    ((float4*)(hsh + i))[0] = src[0];
    ((float4*)(hsh + i))[1] = src[1];
  }
  __syncthreads();

  const int jl = tid & 63, bl = tid >> 6;
  const int gate = jl >> 4, ml = jl & 15;
  const int m = mc * 16 + ml;
  const int j = gate * H_ + m;      // row of W_hh / gate index
  const int b = b4 * 4 + bl;

  float acc = Xg[((size_t)b * T_ + t) * G4_ + j];
  const float4* Wrow = (const float4*)(Whh + (size_t)j * H_);
  const float4* hrow = (const float4*)(hsh + bl * H_);
  #pragma unroll 8
  for (int k = 0; k < 128; ++k) {
    float4 w = Wrow[k];
    float4 h = hrow[k];
    acc += w.x * h.x + w.y * h.y + w.z * h.z + w.w * h.w;
  }
  gsh[bl * 64 + gate * 16 + ml] = acc;
  __syncthreads();

  if (tid < 64) {  // pointwise: one thread per (bl, ml)
    int bl2 = tid >> 4, ml2 = tid & 15;
    int m2 = mc * 16 + ml2;
    int b2 = b4 * 4 + bl2;
    float gi = gsh[bl2 * 64 +  0 + ml2];
    float gf = gsh[bl2 * 64 + 16 + ml2];
    float gg = gsh[bl2 * 64 + 32 + ml2];
    float go = gsh[bl2 * 64 + 48 + ml2];
    float si = 1.f / (1.f + expf(-gi));
    float sf = 1.f / (1.f + expf(-gf));
    float tg = tanhf(gg);
    float so = 1.f / (1.f + expf(-go));
    size_t idx = (size_t)b2 * H_ + m2;
    float c = sf * cbuf[idx] + si * tg;
    cbuf[idx] = c;
    float h = so * tanhf(c);
    hout[idx] = h;
    Hall[((size_t)b2 * T_ + t) * H_ + m2] = (bf16_t)h;
  }
}

// ---------------- launch ----------------

extern "C" void kernel_launch(void* const* d_in, const int* in_sizes, int n_in,
                              void* d_out, int out_size, void* d_ws, size_t ws_size,
                              hipStream_t stream) {
  const float* enc    = (const float*)d_in[0];
  const int*   target = (const int*)  d_in[1];
  const float* E      = (const float*)d_in[2];
  const float* W_ih   = (const float*)d_in[3];
  const float* W_hh   = (const float*)d_in[4];
  const float* b_ih   = (const float*)d_in[5];
  const float* b_hh   = (const float*)d_in[6];
  const float* b_out  = (const float*)d_in[7];
  float* out = (float*)d_out;

  char* p = (char*)d_ws;
  bf16_t* E_bf   = (bf16_t*)p;  p += (size_t)V_ * H_ * 2;        // 32.77 MB
  bf16_t* Wih_bf = (bf16_t*)p;  p += (size_t)G4_ * H_ * 2;       //  2.10 MB
  bf16_t* Xemb   = (bf16_t*)p;  p += (size_t)B_ * T_ * H_ * 2;   //  4.19 MB
  bf16_t* Hall   = (bf16_t*)p;  p += (size_t)B_ * T_ * H_ * 2;   //  4.19 MB
  float*  Xg     = (float*)p;   p += (size_t)B_ * T_ * G4_ * 4;  // 33.55 MB
  float*  hb0    = (float*)p;   p += (size_t)B_ * H_ * 4;
  float*  hb1    = (float*)p;   p += (size_t)B_ * H_ * 4;
  float*  cb     = (float*)p;   p += (size_t)B_ * H_ * 4;
  float*  bsum   = (float*)p;   p += (size_t)G4_ * 4;

  // prep: casts, embedding gather, state init
  convert_f32_bf16<<<2048, 256, 0, stream>>>(E, E_bf, V_ * H_ / 4);
  convert_f32_bf16<<<256, 256, 0, stream>>>(W_ih, Wih_bf, G4_ * H_ / 4);
  gather_embed<<<B_ * T_, 128, 0, stream>>>(E, target, Xemb);
  init_state<<<64, 256, 0, stream>>>(enc, b_ih, b_hh, hb0, cb, bsum);

  // Xg[4096, 2048] = Xemb @ W_ih^T + (b_ih + b_hh)
  dim3 g1(G4_ / 128, (B_ * T_) / 128);
  gemm_bt<<<g1, 256, 0, stream>>>(Xemb, Wih_bf, bsum, Xg, G4_);

  // sequential recurrence, double-buffered h
  for (int t = 0; t < T_; ++t) {
    const float* hi = (t & 1) ? hb1 : hb0;
    float*       ho = (t & 1) ? hb0 : hb1;
    lstm_step<<<256, 256, 0, stream>>>(t, Xg, W_hh, hi, ho, cb, Hall);
  }

  // logits[4096, 32000] = Hall @ E^T + b_out
  dim3 g2(V_ / 128, (B_ * T_) / 128);
  gemm_bt<<<g2, 256, 0, stream>>>(Hall, E_bf, b_out, out, V_);
}